// Round 2
// baseline (1552.906 us; speedup 1.0000x reference)
//
#include <hip/hip_runtime.h>

// HomologicalConnectivityLoss: adj (8192x8192 fp32, bit-exact symmetric).
// loss = (n_comp-1)^2 + max(0, n_edges - N + n_comp)^2
//
// R2: two-phase. R1's fused scan+union ran at 1.5% HBM (620us) because sparse
// edges (0.23%) made ~287K wave-level unite() executions with ~1 active lane,
// each a serialized chain of dependent L2/cross-XCD atomic loads. Now:
//   phase 1: pure streaming triangle scan -> compact edge list (~157K u32)
//   phase 2: union-find over the dense list (2.4K wave-unites, 64 lanes each)
//
// Workspace layout (ints): ws[0]=edge_cnt, ws[1]=diag_cnt, ws[2..2+NN)=parent,
// ws[2+NN..] = edge buffer (u32: (r<<13)|j).

#define NN 8192

__device__ __forceinline__ int ld_parent(int* p, int i) {
    return __hip_atomic_load(&p[i], __ATOMIC_RELAXED, __HIP_MEMORY_SCOPE_AGENT);
}
__device__ __forceinline__ void st_parent(int* p, int i, int v) {
    __hip_atomic_store(&p[i], v, __ATOMIC_RELAXED, __HIP_MEMORY_SCOPE_AGENT);
}

// Path-halving find. Invariant: parent[x] <= x (hooks go hi->lo) -> terminates.
__device__ int find_root(int* parent, int x) {
    int p = ld_parent(parent, x);
    while (p != x) {
        int gp = ld_parent(parent, p);
        if (gp == p) return p;
        st_parent(parent, x, gp);
        x = gp;
        p = ld_parent(parent, x);
    }
    return x;
}

// Lock-free union (ECL-CC style): hook larger root onto smaller via CAS.
__device__ void unite(int* parent, int a, int b) {
    int ra = find_root(parent, a);
    int rb = find_root(parent, b);
    while (ra != rb) {
        int hi = ra > rb ? ra : rb;
        int lo = ra > rb ? rb : ra;
        int prev = atomicCAS(&parent[hi], hi, lo);
        if (prev == hi) return;
        ra = find_root(parent, prev);
        rb = find_root(parent, lo);
    }
}

__global__ __launch_bounds__(256) void init_kernel(int* ws) {
    int i = blockIdx.x * 256 + threadIdx.x;
    if (i < 2) ws[i] = 0;
    if (i < NN) ws[2 + i] = i;   // parent[i] = i
}

// Block b processes rows b and NN-1-b (cols 0..r): perfectly balanced triangle
// scan. Two float4 loads in flight per iteration for MLP. Edges (j<r, v>0) are
// appended to the compact list via per-lane atomicAdd(cnt,1) (compiler
// coalesces to one wave-level add + lane ranks).
__global__ __launch_bounds__(256) void scan_kernel(const float* __restrict__ adj,
                                                   int* __restrict__ counters,
                                                   unsigned int* __restrict__ ebuf,
                                                   int cap) {
    int b = blockIdx.x;
    int c1 = 0;  // diagonal positives

    #pragma unroll
    for (int half = 0; half < 2; ++half) {
        int r = half ? (NN - 1 - b) : b;
        const float4* rowp = (const float4*)(adj + (size_t)r * NN);
        int nf4 = (r + 4) >> 2;   // ceil((r+1)/4)

        auto process = [&](float4 v, int g) {
            int j0 = g << 2;
            float vv[4] = {v.x, v.y, v.z, v.w};
            #pragma unroll
            for (int c = 0; c < 4; ++c) {
                int j = j0 + c;
                bool pos = vv[c] > 0.0f;
                if (pos && j < r) {
                    int idx = atomicAdd(&counters[0], 1);
                    if (idx < cap) ebuf[idx] = ((unsigned)r << 13) | (unsigned)j;
                }
                c1 += (pos && j == r) ? 1 : 0;
            }
        };

        int g = threadIdx.x;
        for (; g + 256 < nf4; g += 512) {
            float4 va = rowp[g];
            float4 vb = rowp[g + 256];
            process(va, g);
            process(vb, g + 256);
        }
        if (g < nf4) process(rowp[g], g);
    }

    #pragma unroll
    for (int off = 32; off > 0; off >>= 1) c1 += __shfl_down(c1, off, 64);
    if ((threadIdx.x & 63) == 0 && c1) atomicAdd(&counters[1], c1);
}

__global__ __launch_bounds__(256) void union_kernel(const unsigned int* __restrict__ ebuf,
                                                    const int* __restrict__ counters,
                                                    int* parent, int cap) {
    int m = counters[0] < cap ? counters[0] : cap;
    for (int i = blockIdx.x * 256 + threadIdx.x; i < m; i += gridDim.x * 256) {
        unsigned int e = ebuf[i];
        unite(parent, (int)(e >> 13), (int)(e & (NN - 1)));
    }
}

__global__ __launch_bounds__(1024) void final_kernel(const int* __restrict__ ws,
                                                     float* __restrict__ out) {
    const int* parent = ws + 2;
    __shared__ int wsum[16];
    int cnt = 0;
    for (int i = threadIdx.x; i < NN; i += 1024)
        cnt += (parent[i] == i) ? 1 : 0;
    #pragma unroll
    for (int off = 32; off > 0; off >>= 1) cnt += __shfl_down(cnt, off, 64);
    if ((threadIdx.x & 63) == 0) wsum[threadIdx.x >> 6] = cnt;
    __syncthreads();
    if (threadIdx.x == 0) {
        int roots = 0;
        #pragma unroll
        for (int w = 0; w < 16; ++w) roots += wsum[w];
        long long total = 2LL * (long long)ws[0] + (long long)ws[1];
        long long n_edges_i = total >> 1;           // exact integer // 2
        double n_comp = (double)roots;
        double comp_loss = (n_comp - 1.0) * (n_comp - 1.0);
        double betti = (double)n_edges_i - (double)NN + n_comp;
        double cyc = betti > 0.0 ? betti : 0.0;
        out[0] = (float)(comp_loss + cyc * cyc);
    }
}

extern "C" void kernel_launch(void* const* d_in, const int* in_sizes, int n_in,
                              void* d_out, int out_size, void* d_ws, size_t ws_size,
                              hipStream_t stream) {
    const float* adj = (const float*)d_in[0];
    int* ws = (int*)d_ws;
    int* counters = ws;                       // [0]=edges, [1]=diag
    int* parent = ws + 2;
    unsigned int* ebuf = (unsigned int*)(ws + 2 + NN);
    long long cap_ll = (long long)(ws_size / 4) - (2 + NN);
    int cap = cap_ll > 0x7fffffff ? 0x7fffffff : (cap_ll < 0 ? 0 : (int)cap_ll);
    float* out = (float*)d_out;

    init_kernel<<<NN / 256, 256, 0, stream>>>(ws);
    scan_kernel<<<NN / 2, 256, 0, stream>>>(adj, counters, ebuf, cap);
    union_kernel<<<1024, 256, 0, stream>>>(ebuf, counters, parent, cap);
    final_kernel<<<1, 1024, 0, stream>>>(ws, out);
}

// Round 3
// 436.950 us; speedup vs baseline: 3.5540x; 3.5540x over previous
//
#include <hip/hip_runtime.h>

// HomologicalConnectivityLoss: adj (8192x8192 fp32, bit-exact symmetric).
// loss = (n_comp-1)^2 + max(0, n_edges - N + n_comp)^2
//
// R3 lessons baked in:
//  - R1: fused global union-find in the streaming scan -> 620us (pointer-chase
//    latency, agent-scope loads ~500cyc each, serialized).
//  - R2: per-edge global atomicAdd append -> 838us scan (single-L2-line RMW
//    serialization), 945us global union (same latency poison).
//  => R3: streaming scan stages edges in LDS, ONE global atomic per block.
//     Union-find runs in a SINGLE block with parent[] entirely in LDS
//     (no cross-XCD coherence concerns, ~60cyc ops instead of ~500cyc),
//     fused with root-count + loss epilogue.
//
// Workspace (ints): ws[0]=lower-edge count, ws[1]=diag count, ws[2..]=edge buf
// (u32 encoded (r<<13)|j, r>j).

#define NN 8192
#define SCAN_LDS_CAP 2048   // expected ~38 edges/block; 2048 = absurd margin

__global__ __launch_bounds__(64) void init_kernel(int* counters) {
    if (threadIdx.x < 2) counters[threadIdx.x] = 0;
}

// Block b processes rows b and NN-1-b (cols 0..r): balanced triangle scan.
// Edges go to an LDS staging buffer (cheap CU-local atomics); one global
// atomicAdd per block reserves ebuf space; coalesced flush.
__global__ __launch_bounds__(256) void scan_kernel(const float* __restrict__ adj,
                                                   int* __restrict__ counters,
                                                   unsigned int* __restrict__ ebuf,
                                                   int cap) {
    __shared__ int lds_n;
    __shared__ int lds_base;
    __shared__ unsigned int lds_e[SCAN_LDS_CAP];
    if (threadIdx.x == 0) lds_n = 0;
    __syncthreads();

    int b = blockIdx.x;
    int c1 = 0;  // diagonal positives
    #pragma unroll
    for (int half = 0; half < 2; ++half) {
        int r = half ? (NN - 1 - b) : b;
        const float4* rowp = (const float4*)(adj + (size_t)r * NN);
        int nf4 = (r + 4) >> 2;   // ceil((r+1)/4)
        for (int g = threadIdx.x; g < nf4; g += 256) {
            float4 v = rowp[g];
            int j0 = g << 2;
            float vv[4] = {v.x, v.y, v.z, v.w};
            #pragma unroll
            for (int c = 0; c < 4; ++c) {
                int j = j0 + c;
                bool pos = vv[c] > 0.0f;
                if (pos && j < r) {
                    int k = atomicAdd(&lds_n, 1);            // LDS atomic: cheap
                    unsigned int e = ((unsigned)r << 13) | (unsigned)j;
                    if (k < SCAN_LDS_CAP) lds_e[k] = e;
                    else {  // never taken in practice; correctness fallback
                        int gk = atomicAdd(counters, 1);
                        if (gk < cap) ebuf[gk] = e;
                    }
                }
                c1 += (pos && j == r) ? 1 : 0;
            }
        }
    }
    // diag count: wave reduce, one atomic per wave
    #pragma unroll
    for (int off = 32; off > 0; off >>= 1) c1 += __shfl_down(c1, off, 64);
    if ((threadIdx.x & 63) == 0 && c1) atomicAdd(counters + 1, c1);

    __syncthreads();
    int n = lds_n < SCAN_LDS_CAP ? lds_n : SCAN_LDS_CAP;
    if (threadIdx.x == 0) lds_base = atomicAdd(counters, n);  // 1 per block
    __syncthreads();
    int base = lds_base;
    for (int k = threadIdx.x; k < n; k += 256) {
        int idx = base + k;
        if (idx < cap) ebuf[idx] = lds_e[k];
    }
}

// LDS union-find helpers. volatile defeats register-caching of parent reads;
// LDS is physically shared within the CU so no cache coherence issues exist.
// Invariant: par[x] <= x (hooks go hi->lo, halving writes ancestors), so every
// traversal strictly decreases -> terminates.
__device__ __forceinline__ int find_lds(volatile int* par, int x) {
    int p = par[x];
    while (p != x) {
        int gp = par[p];
        if (gp == p) return p;
        par[x] = gp;       // path halving (benign race)
        x = gp;
        p = par[x];
    }
    return x;
}

__device__ __forceinline__ void unite_lds(int* par_raw, volatile int* par,
                                          int a, int b) {
    int ra = find_lds(par, a);
    int rb = find_lds(par, b);
    while (ra != rb) {
        int hi = ra > rb ? ra : rb;
        int lo = ra ^ rb ^ hi;
        int prev = atomicCAS(&par_raw[hi], hi, lo);   // LDS CAS
        if (prev == hi) return;
        ra = find_lds(par, prev);
        rb = find_lds(par, lo);
    }
}

// Single block: union-find over the compacted edge list with parent in LDS,
// then root count + loss, all fused.
__global__ __launch_bounds__(1024) void union_final_kernel(
        const unsigned int* __restrict__ ebuf,
        const int* __restrict__ counters,
        int cap, float* __restrict__ out) {
    __shared__ int par[NN];          // 32 KB
    __shared__ int wsum[16];
    volatile int* vpar = par;
    int tid = threadIdx.x;
    for (int i = tid; i < NN; i += 1024) par[i] = i;
    __syncthreads();

    int total_lower = counters[0];
    int m = total_lower < cap ? total_lower : cap;

    const int CH = 16384;   // compress sweep every CH edges keeps depth ~1-2
    for (int base = 0; base < m; base += CH) {
        int hi = base + CH < m ? base + CH : m;
        for (int i = base + tid; i < hi; i += 1024) {
            unsigned int e = ebuf[i];
            unite_lds(par, vpar, (int)(e >> 13), (int)(e & (NN - 1)));
        }
        __syncthreads();
        for (int i = tid; i < NN; i += 1024) par[i] = find_lds(vpar, i);
        __syncthreads();
    }

    // root count
    int cnt = 0;
    for (int i = tid; i < NN; i += 1024) cnt += (par[i] == i) ? 1 : 0;
    #pragma unroll
    for (int off = 32; off > 0; off >>= 1) cnt += __shfl_down(cnt, off, 64);
    if ((tid & 63) == 0) wsum[tid >> 6] = cnt;
    __syncthreads();
    if (tid == 0) {
        int roots = 0;
        #pragma unroll
        for (int w = 0; w < 16; ++w) roots += wsum[w];
        long long total = 2LL * (long long)total_lower + (long long)counters[1];
        long long n_edges_i = total >> 1;               // exact integer // 2
        double n_comp = (double)roots;
        double comp_loss = (n_comp - 1.0) * (n_comp - 1.0);
        double betti = (double)n_edges_i - (double)NN + n_comp;
        double cyc = betti > 0.0 ? betti : 0.0;
        out[0] = (float)(comp_loss + cyc * cyc);
    }
}

extern "C" void kernel_launch(void* const* d_in, const int* in_sizes, int n_in,
                              void* d_out, int out_size, void* d_ws, size_t ws_size,
                              hipStream_t stream) {
    const float* adj = (const float*)d_in[0];
    int* ws = (int*)d_ws;
    int* counters = ws;                       // [0]=lower edges, [1]=diag
    unsigned int* ebuf = (unsigned int*)(ws + 2);
    long long cap_ll = (long long)(ws_size / 4) - 2;
    int cap = cap_ll > 0x7fffffff ? 0x7fffffff : (cap_ll < 0 ? 0 : (int)cap_ll);
    float* out = (float*)d_out;

    init_kernel<<<1, 64, 0, stream>>>(counters);
    scan_kernel<<<NN / 2, 256, 0, stream>>>(adj, counters, ebuf, cap);
    union_final_kernel<<<1, 1024, 0, stream>>>(ebuf, counters, cap, out);
}

// Round 4
// 414.477 us; speedup vs baseline: 3.7467x; 1.0542x over previous
//
#include <hip/hip_runtime.h>

// HomologicalConnectivityLoss: adj (8192x8192 fp32, bit-exact symmetric).
// loss = (n_comp-1)^2 + max(0, n_edges - N + n_comp)^2
//
// Ladder so far:
//  R1 767us: fused global union-find in scan -> agent-scope pointer-chase.
//  R2 1553us: per-edge global atomicAdd append (single-L2-line RMW serialization)
//             + global union-find (latency poison).
//  R3 437us: LDS edge staging (1 global atomic/block) + single-block LDS
//            union-find. Both kernels ~100-160us: union-find's divergent
//            dependent-LDS-read chains and scan's 1-load-in-flight loop.
//  R4: (a) union-find -> Shiloach-Vishkin min-label propagation in LDS:
//          2 independent LDS atomicMins per edge (no loops, no divergence,
//          pipelined), + pointer-jumping shortcut pass => O(log n) rounds.
//      (b) scan: 4 float4 loads in flight per thread.
//
// Workspace (ints): ws[0]=lower-edge count, ws[1]=diag count,
// ws[2..] = edge buffer (u32 encoded (r<<13)|j, r>j).

#define NN 8192
#define SCAN_LDS_CAP 2048   // expected ~38 edges/block; huge margin

__global__ __launch_bounds__(64) void init_kernel(int* counters) {
    if (threadIdx.x < 2) counters[threadIdx.x] = 0;
}

// Block b processes rows b and NN-1-b (cols 0..r): balanced triangle scan.
// Edges staged in LDS (CU-local atomics), one global atomicAdd per block,
// coalesced flush. 4 float4 loads in flight per thread for latency hiding.
__global__ __launch_bounds__(256) void scan_kernel(const float* __restrict__ adj,
                                                   int* __restrict__ counters,
                                                   unsigned int* __restrict__ ebuf,
                                                   int cap) {
    __shared__ int lds_n;
    __shared__ int lds_base;
    __shared__ unsigned int lds_e[SCAN_LDS_CAP];
    if (threadIdx.x == 0) lds_n = 0;
    __syncthreads();

    int b = blockIdx.x;
    int c1 = 0;  // diagonal positives

    #pragma unroll
    for (int half = 0; half < 2; ++half) {
        int r = half ? (NN - 1 - b) : b;
        const float4* rowp = (const float4*)(adj + (size_t)r * NN);
        int nf4 = (r + 4) >> 2;   // ceil((r+1)/4)

        auto process = [&](float4 v, int g) {
            int j0 = g << 2;
            float vv[4] = {v.x, v.y, v.z, v.w};
            #pragma unroll
            for (int c = 0; c < 4; ++c) {
                int j = j0 + c;
                bool pos = vv[c] > 0.0f;
                if (pos && j < r) {
                    int k = atomicAdd(&lds_n, 1);   // LDS atomic: CU-local
                    unsigned int e = ((unsigned)r << 13) | (unsigned)j;
                    if (k < SCAN_LDS_CAP) lds_e[k] = e;
                    else {  // never taken in practice; correctness fallback
                        int gk = atomicAdd(counters, 1);
                        if (gk < cap) ebuf[gk] = e;
                    }
                }
                c1 += (pos && j == r) ? 1 : 0;
            }
        };

        int g = threadIdx.x;
        for (; g + 768 < nf4; g += 1024) {      // 4 loads in flight
            float4 v0 = rowp[g];
            float4 v1 = rowp[g + 256];
            float4 v2 = rowp[g + 512];
            float4 v3 = rowp[g + 768];
            process(v0, g);
            process(v1, g + 256);
            process(v2, g + 512);
            process(v3, g + 768);
        }
        for (; g < nf4; g += 256) process(rowp[g], g);
    }

    // diag count: wave reduce, one atomic per wave
    #pragma unroll
    for (int off = 32; off > 0; off >>= 1) c1 += __shfl_down(c1, off, 64);
    if ((threadIdx.x & 63) == 0 && c1) atomicAdd(counters + 1, c1);

    __syncthreads();
    int n = lds_n < SCAN_LDS_CAP ? lds_n : SCAN_LDS_CAP;
    if (threadIdx.x == 0) lds_base = atomicAdd(counters, n);  // 1 per block
    __syncthreads();
    int base = lds_base;
    for (int k = threadIdx.x; k < n; k += 256) {
        int idx = base + k;
        if (idx < cap) ebuf[idx] = lds_e[k];
    }
}

// Single block: min-label propagation over the compact edge list, labels in
// LDS. Relax pass = 2 independent LDS atomicMins per edge (no divergent
// dependent chains). Shortcut pass = pointer jumping (lab[i]=lab[lab[i]];
// sound: label values are always node indices of the SAME component and only
// decrease). Fixpoint: exactly one node per component has lab[i]==i (the min).
__global__ __launch_bounds__(1024) void label_final_kernel(
        const unsigned int* __restrict__ ebuf,
        const int* __restrict__ counters,
        int cap, float* __restrict__ out) {
    __shared__ int lab[NN];          // 32 KB
    __shared__ int changed;
    __shared__ int wsum[16];
    int tid = threadIdx.x;
    for (int i = tid; i < NN; i += 1024) lab[i] = i;
    __syncthreads();

    int total_lower = counters[0];
    int m = total_lower < cap ? total_lower : cap;

    for (;;) {
        if (tid == 0) changed = 0;
        __syncthreads();

        // relax: per edge, push the smaller endpoint label to the larger
        for (int i = tid; i < m; i += 1024) {
            unsigned int e = ebuf[i];
            int r = (int)(e >> 13);
            int j = (int)(e & (NN - 1));
            int lr = lab[r];
            int lj = lab[j];
            if (lj < lr) {
                int old = atomicMin(&lab[r], lj);
                if (lj < old) changed = 1;
            } else if (lr < lj) {
                int old = atomicMin(&lab[j], lr);
                if (lr < old) changed = 1;
            }
        }
        __syncthreads();

        // shortcut: pointer jumping (monotone, benign races)
        for (int i = tid; i < NN; i += 1024) {
            int l = lab[i];
            int ll = lab[l];
            if (ll < l) { lab[i] = ll; changed = 1; }
        }
        __syncthreads();

        if (changed == 0) break;   // uniform decision (post-barrier read)
        __syncthreads();           // protect next round's reset vs this read
    }

    // count self-labeled nodes = component count
    int cnt = 0;
    for (int i = tid; i < NN; i += 1024) cnt += (lab[i] == i) ? 1 : 0;
    #pragma unroll
    for (int off = 32; off > 0; off >>= 1) cnt += __shfl_down(cnt, off, 64);
    if ((tid & 63) == 0) wsum[tid >> 6] = cnt;
    __syncthreads();
    if (tid == 0) {
        int roots = 0;
        #pragma unroll
        for (int w = 0; w < 16; ++w) roots += wsum[w];
        long long total = 2LL * (long long)total_lower + (long long)counters[1];
        long long n_edges_i = total >> 1;               // exact integer // 2
        double n_comp = (double)roots;
        double comp_loss = (n_comp - 1.0) * (n_comp - 1.0);
        double betti = (double)n_edges_i - (double)NN + n_comp;
        double cyc = betti > 0.0 ? betti : 0.0;
        out[0] = (float)(comp_loss + cyc * cyc);
    }
}

extern "C" void kernel_launch(void* const* d_in, const int* in_sizes, int n_in,
                              void* d_out, int out_size, void* d_ws, size_t ws_size,
                              hipStream_t stream) {
    const float* adj = (const float*)d_in[0];
    int* ws = (int*)d_ws;
    int* counters = ws;                       // [0]=lower edges, [1]=diag
    unsigned int* ebuf = (unsigned int*)(ws + 2);
    long long cap_ll = (long long)(ws_size / 4) - 2;
    int cap = cap_ll > 0x7fffffff ? 0x7fffffff : (cap_ll < 0 ? 0 : (int)cap_ll);
    float* out = (float*)d_out;

    init_kernel<<<1, 64, 0, stream>>>(counters);
    scan_kernel<<<NN / 2, 256, 0, stream>>>(adj, counters, ebuf, cap);
    label_final_kernel<<<1, 1024, 0, stream>>>(ebuf, counters, cap, out);
}